// Round 8
// baseline (1621.346 us; speedup 1.0000x reference)
//
#include <hip/hip_runtime.h>
#include <hip/hip_bf16.h>
#include <math.h>

#define B_ 16
#define T_ 128
#define S_ 256
#define H_ 512
#define M_ 512
#define V_ 32000

typedef __attribute__((ext_vector_type(8))) short short8v;
typedef __attribute__((ext_vector_type(4))) float float4v;

// ---------------- embedding gather ----------------
__global__ __launch_bounds__(128) void k_gather(const int* __restrict__ tgt,
    const float* __restrict__ embed, float* __restrict__ x)
{
  const int row = blockIdx.x;          // b*T+t
  const int v = tgt[row];
  const float4* src = (const float4*)(embed + (size_t)v * H_);
  float4* dst = (float4*)(x + (size_t)row * H_);
  dst[threadIdx.x] = src[threadIdx.x];
}

// ---------------- f32 NT GEMM + bias (xg0 only) ----------------
__global__ __launch_bounds__(256) void k_gemm_nt_bias(const float* __restrict__ A,
    const float* __restrict__ Bm, const float* __restrict__ bias,
    float* __restrict__ C, int N)
{
  __shared__ float As[64][33];
  __shared__ float Bs[64][33];
  const int tid = threadIdx.x;
  const int tm = tid >> 4, tn = tid & 15;
  const float* Ab = A  + (size_t)blockIdx.y * 64 * 512;
  const float* Bb = Bm + (size_t)blockIdx.x * 64 * 512;
  float acc00=0.f,acc01=0.f,acc02=0.f,acc03=0.f;
  float acc10=0.f,acc11=0.f,acc12=0.f,acc13=0.f;
  float acc20=0.f,acc21=0.f,acc22=0.f,acc23=0.f;
  float acc30=0.f,acc31=0.f,acc32=0.f,acc33=0.f;
  for (int k0 = 0; k0 < 512; k0 += 32) {
#pragma unroll
    for (int i = 0; i < 8; ++i) {
      int v = tid + i * 256;
      int row = v >> 5, col = v & 31;
      As[row][col] = Ab[(size_t)row * 512 + k0 + col];
      Bs[row][col] = Bb[(size_t)row * 512 + k0 + col];
    }
    __syncthreads();
#pragma unroll
    for (int kk = 0; kk < 32; ++kk) {
      float a0 = As[tm*4+0][kk], a1 = As[tm*4+1][kk];
      float a2 = As[tm*4+2][kk], a3 = As[tm*4+3][kk];
      float b0 = Bs[tn*4+0][kk], b1 = Bs[tn*4+1][kk];
      float b2 = Bs[tn*4+2][kk], b3 = Bs[tn*4+3][kk];
      acc00 += a0*b0; acc01 += a0*b1; acc02 += a0*b2; acc03 += a0*b3;
      acc10 += a1*b0; acc11 += a1*b1; acc12 += a1*b2; acc13 += a1*b3;
      acc20 += a2*b0; acc21 += a2*b1; acc22 += a2*b2; acc23 += a2*b3;
      acc30 += a3*b0; acc31 += a3*b1; acc32 += a3*b2; acc33 += a3*b3;
    }
    __syncthreads();
  }
  const int mbase = blockIdx.y*64 + tm*4;
  const int nbase = blockIdx.x*64 + tn*4;
  float bj0 = bias[nbase+0], bj1 = bias[nbase+1], bj2 = bias[nbase+2], bj3 = bias[nbase+3];
  float* Cr0 = C + (size_t)(mbase+0)*N + nbase;
  float* Cr1 = C + (size_t)(mbase+1)*N + nbase;
  float* Cr2 = C + (size_t)(mbase+2)*N + nbase;
  float* Cr3 = C + (size_t)(mbase+3)*N + nbase;
  Cr0[0]=acc00+bj0; Cr0[1]=acc01+bj1; Cr0[2]=acc02+bj2; Cr0[3]=acc03+bj3;
  Cr1[0]=acc10+bj0; Cr1[1]=acc11+bj1; Cr1[2]=acc12+bj2; Cr1[3]=acc13+bj3;
  Cr2[0]=acc20+bj0; Cr2[1]=acc21+bj1; Cr2[2]=acc22+bj2; Cr2[3]=acc23+bj3;
  Cr3[0]=acc30+bj0; Cr3[1]=acc31+bj1; Cr3[2]=acc32+bj2; Cr3[3]=acc33+bj3;
}

// bulk coherent load: 8x dwordx4, LLC-visible (sc0 sc1), waitcnt inside asm.
__device__ inline void bulk8_to_lds(const float* rowbase, int sc, float* dstrow)
{
  const float* p = rowbase + sc * 4;
  float4 a, b, c, d, e, f, g, h;
  asm volatile(
    "global_load_dwordx4 %0, %[p], off sc0 sc1\n\t"
    "global_load_dwordx4 %1, %[p], off offset:256 sc0 sc1\n\t"
    "global_load_dwordx4 %2, %[p], off offset:512 sc0 sc1\n\t"
    "global_load_dwordx4 %3, %[p], off offset:768 sc0 sc1\n\t"
    "global_load_dwordx4 %4, %[p], off offset:1024 sc0 sc1\n\t"
    "global_load_dwordx4 %5, %[p], off offset:1280 sc0 sc1\n\t"
    "global_load_dwordx4 %6, %[p], off offset:1536 sc0 sc1\n\t"
    "global_load_dwordx4 %7, %[p], off offset:1792 sc0 sc1\n\t"
    "s_waitcnt vmcnt(0)"
    : "=&v"(a), "=&v"(b), "=&v"(c), "=&v"(d),
      "=&v"(e), "=&v"(f), "=&v"(g), "=&v"(h)
    : [p]"v"(p)
    : "memory");
  *(float4*)&dstrow[(0*16 + sc) * 4] = a;
  *(float4*)&dstrow[(1*16 + sc) * 4] = b;
  *(float4*)&dstrow[(2*16 + sc) * 4] = c;
  *(float4*)&dstrow[(3*16 + sc) * 4] = d;
  *(float4*)&dstrow[(4*16 + sc) * 4] = e;
  *(float4*)&dstrow[(5*16 + sc) * 4] = f;
  *(float4*)&dstrow[(6*16 + sc) * 4] = g;
  *(float4*)&dstrow[(7*16 + sc) * 4] = h;
}

__device__ inline float4 load16_coh(const float* p)
{
  float4 v;
  asm volatile(
    "global_load_dwordx4 %0, %1, off sc0 sc1\n\t"
    "s_waitcnt vmcnt(0)"
    : "=v"(v) : "v"(p) : "memory");
  return v;
}

// ---------------- fused 2-layer GRU + attention workers ----------------
// Grid 256 x 256 thr. WGs [0,64): layer 0 (8 dims). WGs [64,192): layer 1 (4 dims).
// WGs [192,256): attention workers — WG w handles t = w-192 and w-128: polls the
// 128 fB[t] flags (FMA-burn while waiting = heater), coherent-loads y1 rows,
// computes softmax+context, writes attn_out. Attn rides inside the GRU shadow.
__global__ __launch_bounds__(256) void k_gru2(
    const float* __restrict__ xg0,
    const float* __restrict__ Whh0, const float* __restrict__ bhh0,
    const float* __restrict__ Wih1, const float* __restrict__ bih1,
    const float* __restrict__ Whh1, const float* __restrict__ bhh1,
    const float* __restrict__ hidden, const float* __restrict__ enc,
    float* __restrict__ out0, float* __restrict__ y1, float* __restrict__ hn,
    float* __restrict__ aout,
    unsigned int* __restrict__ fA, unsigned int* __restrict__ fB)
{
  __shared__ float Wl[24][520];
  __shared__ float hx[2][16 * 520];
  __shared__ float ps[24][16][17];
  __shared__ float orow[520];
  __shared__ float wbuf[256];
  __shared__ float red[8];
  const int bid = blockIdx.x;
  const int lt = threadIdx.x;

  // ---------------- attention workers ----------------
  if (bid >= 192) {
    const int w = bid - 192;
    for (int tt = w; tt < T_; tt += 64) {
      // wait for all 128 L1 flags of step tt (burn FMAs while polling)
      if (lt < 128) {
        const unsigned int* fl = &fB[tt * 128 + lt];
        float a0 = 1.0f + lt, a1 = 2.0f + lt, a2 = 3.0f, a3 = 4.0f;
        while (__hip_atomic_load(fl, __ATOMIC_RELAXED, __HIP_MEMORY_SCOPE_AGENT) == 0u) {
#pragma unroll 8
          for (int i = 0; i < 128; ++i) {
            a0 = __builtin_fmaf(a0, 1.0001f, 0.9999f);
            a1 = __builtin_fmaf(a1, 1.0001f, 0.9999f);
            a2 = __builtin_fmaf(a2, 1.0001f, 0.9999f);
            a3 = __builtin_fmaf(a3, 1.0001f, 0.9999f);
          }
          asm volatile("" :: "v"(a0), "v"(a1), "v"(a2), "v"(a3));
          __builtin_amdgcn_s_sleep(4);
        }
      }
      __syncthreads();
      for (int b = 0; b < 16; ++b) {
        const size_t row = (size_t)(b * T_ + tt);
        if (lt < 128)
          *(float4*)&orow[lt * 4] = load16_coh(y1 + row * 512 + lt * 4);
        __syncthreads();
        // scores: thread = source position s
        const float* er = enc + (size_t)(b * S_ + lt) * 512;
        float acc = 0.f;
        for (int k = 0; k < 512; k += 4) {
          float4 e = *(const float4*)(er + k);
          acc += orow[k]*e.x + orow[k+1]*e.y + orow[k+2]*e.z + orow[k+3]*e.w;
        }
        float m = acc;
#pragma unroll
        for (int off = 32; off > 0; off >>= 1) m = fmaxf(m, __shfl_down(m, off));
        if ((lt & 63) == 0) red[lt >> 6] = m;
        __syncthreads();
        float mx = fmaxf(fmaxf(red[0], red[1]), fmaxf(red[2], red[3]));
        float e = expf(acc - mx);
        wbuf[lt] = e;
        float s = e;
#pragma unroll
        for (int off = 32; off > 0; off >>= 1) s += __shfl_down(s, off);
        if ((lt & 63) == 0) red[4 + (lt >> 6)] = s;
        __syncthreads();
        const float inv = 1.f / (red[4] + red[5] + red[6] + red[7]);
        const int kk = lt * 2;
        float c0 = 0.f, c1 = 0.f;
        for (int s2 = 0; s2 < S_; ++s2) {
          float ws = wbuf[s2];
          float2 ev = *(const float2*)(enc + (size_t)(b * S_ + s2) * 512 + kk);
          c0 += ws * ev.x; c1 += ws * ev.y;
        }
        aout[row * 512 + kk]     = orow[kk]     + c0 * inv;
        aout[row * 512 + kk + 1] = orow[kk + 1] + c1 * inv;
        __syncthreads();      // protect orow/wbuf before next b
      }
    }
    return;
  }

  const bool isB = bid >= 64;
  const int wg = isB ? bid - 64 : bid;
  const int dbase = isB ? wg * 4 : wg * 8;

  for (int r = 0; r < 24; ++r) {
    const float* src;
    if (!isB) src = Whh0 + (size_t)((r >> 3) * 512 + dbase + (r & 7)) * 512;
    else if (r < 12) src = Whh1 + (size_t)((r >> 2) * 512 + dbase + (r & 3)) * 512;
    else { int rr = r - 12; src = Wih1 + (size_t)((rr >> 2) * 512 + dbase + (rr & 3)) * 512; }
    Wl[r][lt] = src[lt];
    Wl[r][lt + 256] = src[lt + 256];
  }

  const int kq = lt & 15;
  const int bq = (lt >> 4) & 3;
  const int rgrp = lt >> 6;
  const int sb = lt >> 4;
  const int sc = lt & 15;
  float* ybuf = isB ? y1 : out0;
  const float* h0g = hidden + (isB ? 8192 : 0);

  const int rb = isB ? (lt >> 2) : (lt >> 3);
  const int rdl = isB ? (lt & 3) : (lt & 7);
  const int rdg = dbase + rdl;
  const int nred = isB ? 64 : 128;
  float bhr = 0.f, bhz = 0.f, bhn = 0.f, bir = 0.f, biz = 0.f, bin_ = 0.f;
  if (lt < nred) {
    const float* bhh = isB ? bhh1 : bhh0;
    bhr = bhh[rdg]; bhz = bhh[512 + rdg]; bhn = bhh[1024 + rdg];
    if (isB) { bir = bih1[rdg]; biz = bih1[512 + rdg]; bin_ = bih1[1024 + rdg]; }
  }

  for (int t = 0; t < T_; ++t) {
    // ---- P: poll flags ----
    if (!isB) {
      if (t > 0 && lt < 64) {
        unsigned v;
        do {
          v = __hip_atomic_load(&fA[(t - 1) * 64 + lt], __ATOMIC_RELAXED, __HIP_MEMORY_SCOPE_AGENT);
          if (__all(v != 0u)) break;
          __builtin_amdgcn_s_sleep(1);
        } while (true);
      }
    } else {
      if (lt < 64) {
        unsigned v;
        do {
          v = __hip_atomic_load(&fA[t * 64 + lt], __ATOMIC_RELAXED, __HIP_MEMORY_SCOPE_AGENT);
          if (__all(v != 0u)) break;
          __builtin_amdgcn_s_sleep(1);
        } while (true);
      } else if (t > 0 && lt < 192) {
        unsigned v;
        do {
          v = __hip_atomic_load(&fB[(t - 1) * 128 + (lt - 64)], __ATOMIC_RELAXED, __HIP_MEMORY_SCOPE_AGENT);
          if (__all(v != 0u)) break;
          __builtin_amdgcn_s_sleep(1);
        } while (true);
      }
    }
    __syncthreads();                                   // B0

    // ---- S: bulk-stage h rows ----
    if (t == 0) {
#pragma unroll
      for (int j = 0; j < 8; ++j)
        *(float4*)&hx[0][sb * 520 + (j * 16 + sc) * 4] =
            *(const float4*)(h0g + sb * 512 + (j * 16 + sc) * 4);
    } else {
      bulk8_to_lds(ybuf + (size_t)(sb * T_ + t - 1) * 512, sc, &hx[0][sb * 520]);
    }
    if (isB)
      bulk8_to_lds(out0 + (size_t)(sb * T_ + t) * 512, sc, &hx[1][sb * 520]);
    __syncthreads();                                   // B1

    // ---- M: register-tiled matvec ----
    const float* inb = (isB && rgrp >= 2) ? &hx[1][0] : &hx[0][0];
    float acc[6][4];
#pragma unroll
    for (int jr = 0; jr < 6; ++jr)
#pragma unroll
      for (int jb = 0; jb < 4; ++jb) acc[jr][jb] = 0.f;
#pragma unroll
    for (int i = 0; i < 8; ++i) {
      const int kb = kq * 4 + i * 64;
      float4 hv0 = *(const float4*)(inb + (bq * 4 + 0) * 520 + kb);
      float4 hv1 = *(const float4*)(inb + (bq * 4 + 1) * 520 + kb);
      float4 hv2 = *(const float4*)(inb + (bq * 4 + 2) * 520 + kb);
      float4 hv3 = *(const float4*)(inb + (bq * 4 + 3) * 520 + kb);
#pragma unroll
      for (int jr = 0; jr < 6; ++jr) {
        float4 wv = *(const float4*)(&Wl[rgrp * 6 + jr][kb]);
        acc[jr][0] += wv.x*hv0.x + wv.y*hv0.y + wv.z*hv0.z + wv.w*hv0.w;
        acc[jr][1] += wv.x*hv1.x + wv.y*hv1.y + wv.z*hv1.z + wv.w*hv1.w;
        acc[jr][2] += wv.x*hv2.x + wv.y*hv2.y + wv.z*hv2.z + wv.w*hv2.w;
        acc[jr][3] += wv.x*hv3.x + wv.y*hv3.y + wv.z*hv3.z + wv.w*hv3.w;
      }
    }
#pragma unroll
    for (int jr = 0; jr < 6; ++jr)
#pragma unroll
      for (int jb = 0; jb < 4; ++jb)
        ps[rgrp * 6 + jr][bq * 4 + jb][kq] = acc[jr][jb];
    __syncthreads();                                   // B2

    // ---- R: reduce + activations + store ----
    if (lt < nred) {
      float ghr, ghz, ghn, ixr, ixz, ixn;
      if (!isB) {
        float s0 = 0.f, s1 = 0.f, s2 = 0.f;
#pragma unroll
        for (int q = 0; q < 16; ++q) {
          s0 += ps[rdl][rb][q];
          s1 += ps[8 + rdl][rb][q];
          s2 += ps[16 + rdl][rb][q];
        }
        ghr = s0 + bhr; ghz = s1 + bhz; ghn = s2 + bhn;
        const float* xrow = xg0 + (size_t)(rb * T_ + t) * 1536;
        ixr = xrow[rdg]; ixz = xrow[512 + rdg]; ixn = xrow[1024 + rdg];
      } else {
        float s0=0.f,s1=0.f,s2=0.f,s3=0.f,s4=0.f,s5=0.f;
#pragma unroll
        for (int q = 0; q < 16; ++q) {
          s0 += ps[rdl][rb][q];       s1 += ps[4 + rdl][rb][q];  s2 += ps[8 + rdl][rb][q];
          s3 += ps[12 + rdl][rb][q];  s4 += ps[16 + rdl][rb][q]; s5 += ps[20 + rdl][rb][q];
        }
        ghr = s0 + bhr; ghz = s1 + bhz; ghn = s2 + bhn;
        ixr = s3 + bir; ixz = s4 + biz; ixn = s5 + bin_;
      }
      float rr = 1.f / (1.f + expf(-(ixr + ghr)));
      float zz = 1.f / (1.f + expf(-(ixz + ghz)));
      float nn = tanhf(ixn + rr * ghn);
      float hp = hx[0][rb * 520 + rdg];
      float hnew = (1.f - zz) * nn + zz * hp;
      __hip_atomic_store(&ybuf[(size_t)(rb * T_ + t) * 512 + rdg], hnew,
                         __ATOMIC_RELAXED, __HIP_MEMORY_SCOPE_AGENT);
      if (t == T_ - 1) hn[(isB ? 8192 : 0) + rb * 512 + rdg] = hnew;
    }
    __syncthreads();                                   // B3: vmcnt(0) drain
    if (lt == 0) {
      if (isB)
        __hip_atomic_store(&fB[t * 128 + wg], 1u, __ATOMIC_RELAXED, __HIP_MEMORY_SCOPE_AGENT);
      else
        __hip_atomic_store(&fA[t * 64 + wg], 1u, __ATOMIC_RELAXED, __HIP_MEMORY_SCOPE_AGENT);
    }
  }
}

// ---------------- persistent-B bf16 MFMA logits GEMM ----------------
// Grid 250 x 256. Each WG owns one N-tile (128 cols); B-tile converted to bf16
// ONCE into 128 KB LDS (XOR-swizzled, T2); loops 16 M-tiles with A streamed in
// 64-wide k-chunks (16 KB LDS, same swizzle). MFMA k-order identical to r7.
__global__ __launch_bounds__(256) void k_logits(const float* __restrict__ A,
    const float* __restrict__ Bm, const float* __restrict__ bias,
    float* __restrict__ C)
{
  __shared__ unsigned short Bs[128 * 512];   // swizzled: byte ^= (row&7)<<4
  __shared__ unsigned short As[128 * 64];
  const int tid = threadIdx.x;
  const int nbase = blockIdx.x * 128;
  const int wv = tid >> 6;
  const int l  = tid & 63;
  const int wr = wv >> 1, wc = wv & 1;
  const int r = l & 15, q = l >> 4;

  // ---- stage whole B tile (128 rows x 512 k) as bf16, swizzled ----
  for (int i = 0; i < 32; ++i) {
    const int gid = tid + i * 256;          // 8192 groups of 8 shorts
    const int row = gid >> 6, cg = gid & 63;
    const float* Bg = Bm + (size_t)(nbase + row) * 512 + cg * 8;
    float4 g0 = *(const float4*)(Bg);
    float4 g1 = *(const float4*)(Bg + 4);
    union { short8v v; __hip_bfloat162 h2[4]; } pb;
    pb.h2[0] = __float22bfloat162_rn({g0.x, g0.y});
    pb.h2[1] = __float22bfloat162_rn({g0.z, g0.w});
    pb.h2[2] = __float22bfloat162_rn({g1.x, g1.y});
    pb.h2[3] = __float22bfloat162_rn({g1.z, g1.w});
    const int byte = (row * 1024 + cg * 16) ^ ((row & 7) << 4);
    *(short8v*)&Bs[byte >> 1] = pb.v;
  }
  __syncthreads();

  for (int m = 0; m < 16; ++m) {
    const int mbase = m * 128;
    float4v acc[4][4];
#pragma unroll
    for (int mi = 0; mi < 4; ++mi)
#pragma unroll
      for (int ni = 0; ni < 4; ++ni)
        acc[mi][ni] = (float4v){0.f, 0.f, 0.f, 0.f};

    for (int kc = 0; kc < 8; ++kc) {        // k-chunks of 64
      // stage A chunk: 128 rows x 64 k, swizzled
#pragma unroll
      for (int i = 0; i < 4; ++i) {
        const int gid = tid + i * 256;      // 1024 groups of 8 shorts
        const int row = gid >> 3, cg = gid & 7;
        const float* Ag = A + (size_t)(mbase + row) * 512 + kc * 64 + cg * 8;
        float4 f0 = *(const float4*)(Ag);
        float4 f1 = *(const float4*)(Ag + 4);
        union { short8v v; __hip_bfloat162 h2[4]; } pa;
        pa.h2[0] = __float22bfloat162_rn({f0.x, f0.y});
        pa.h2[1] = __float22bfloat162_rn({f0.z, f0.w});
        pa.h2[2] = __float22bfloat162_rn({f1.x, f1.y});
        pa.h2[3] = __float22bfloat162_rn({f1.z, f1.w});
        const int byte = (row * 128 + cg * 16) ^ ((row & 7) << 4);
        *(short8v*)&As[byte >> 1] = pa.v;
      }
      __syncthreads();

#pragma unroll
      for (int k0s = 0; k0s < 2; ++k0s) {   // two 32-k MFMA steps per chunk
        short8v af[4], bf[4];
#pragma unroll
        for (int mi = 0; mi < 4; ++mi) {
          const int row = wr * 64 + mi * 16 + r;
          const int byte = (row * 128 + k0s * 64 + q * 16) ^ ((row & 7) << 4);
          af[mi] = *(short8v*)&As[byte >> 1];
        }
#pragma unroll
        for (int ni = 0; ni < 4; ++ni) {
          const int row = wc * 64 + ni * 16 + r;
          const int byte = (row * 1024 + kc * 128 + k0s * 64 + q * 16) ^ ((row & 7) << 4);
          bf[ni] = *(short8v*)&Bs[byte >> 1];
        }
#pragma unroll
        for (int mi = 0; mi < 4; ++mi)
#pragma unroll
          for (int ni = 0; ni < 4; ++ni)
            acc[mi][ni] = __builtin_amdgcn_mfma_f32_16x16x32_bf16(af[mi], bf[ni], acc[mi][ni], 0, 0, 0);
      }
      __syncthreads();
    }

    const int mg = mbase + wr * 64;
    const int ng = nbase + wc * 64;
#pragma unroll
    for (int ni = 0; ni < 4; ++ni) {
      const int col = ng + ni * 16 + r;
      const float bj = bias[col];
#pragma unroll
      for (int mi = 0; mi < 4; ++mi) {
        const int rowb = mg + mi * 16 + q * 4;
        float4v v = acc[mi][ni];
        C[(size_t)(rowb + 0) * V_ + col] = v[0] + bj;
        C[(size_t)(rowb + 1) * V_ + col] = v[1] + bj;
        C[(size_t)(rowb + 2) * V_ + col] = v[2] + bj;
        C[(size_t)(rowb + 3) * V_ + col] = v[3] + bj;
      }
    }
  }
}

extern "C" void kernel_launch(void* const* d_in, const int* in_sizes, int n_in,
                              void* d_out, int out_size, void* d_ws, size_t ws_size,
                              hipStream_t stream)
{
  const int*   tgt    = (const int*)  d_in[0];
  const float* hidden = (const float*)d_in[1];
  const float* enc    = (const float*)d_in[2];
  const float* embed  = (const float*)d_in[3];
  const float* W_ih0  = (const float*)d_in[4];
  const float* W_hh0  = (const float*)d_in[5];
  const float* b_ih0  = (const float*)d_in[6];
  const float* b_hh0  = (const float*)d_in[7];
  const float* W_ih1  = (const float*)d_in[8];
  const float* W_hh1  = (const float*)d_in[9];
  const float* b_ih1  = (const float*)d_in[10];
  const float* b_hh1  = (const float*)d_in[11];
  const float* W_out  = (const float*)d_in[12];
  const float* b_out  = (const float*)d_in[13];
  float* out = (float*)d_out;

  float* ws   = (float*)d_ws;
  float* xbuf = ws;                          // 2048*512   (x, later attn_out)
  float* xg   = ws + 1048576;                // 2048*1536
  float* out0 = xg + 3145728;                // 2048*512
  float* y1   = out0 + 1048576;              // 2048*512
  unsigned int* fA = (unsigned int*)(y1 + 1048576);   // 128*64 flags
  unsigned int* fB = fA + T_ * 64;                    // 128*128 flags

  const size_t logitsN = (size_t)(B_*T_) * V_;
  float* hn = out + logitsN;
  float* cn = hn + 16384;

  hipMemsetAsync(fA, 0, (size_t)(T_ * 64 + T_ * 128) * sizeof(unsigned int), stream);
  hipMemsetAsync(cn, 0, (size_t)16384 * sizeof(float), stream);

  k_gather<<<dim3(B_*T_), dim3(128), 0, stream>>>(tgt, embed, xbuf);
  k_gemm_nt_bias<<<dim3(1536/64, (B_*T_)/64), dim3(256), 0, stream>>>(xbuf, W_ih0, b_ih0, xg, 1536);
  k_gru2<<<dim3(256), dim3(256), 0, stream>>>(xg, W_hh0, b_hh0, W_ih1, b_ih1,
                                              W_hh1, b_hh1, hidden, enc,
                                              out0, y1, hn, xbuf, fA, fB);
  k_logits<<<dim3(V_/128), dim3(256), 0, stream>>>(xbuf, W_out, b_out, out);
}